// Round 10
// baseline (167.540 us; speedup 1.0000x reference)
//
#include <hip/hip_runtime.h>
#include <hip/hip_bf16.h>

// EdgeNet fused 2-layer MLP, MI355X (gfx950) — round 10.
//
// out[m][n2] = relu( W2 · relu( W1' · child[m] + b1 ) + b2 ),  W1' = W1 ⊙ parent
//
// R9 post-mortem: 2 blocks/CU bought nothing -> shared-resource bound. LDS
// traffic accounting: N-split-8 makes every wave read the whole x-tile AND
// whole hf-tile => 576 KB/tile ~= 45-64% of CU cycles. Barriers drain vmcnt.
// R10:
//  * 2M x 4N wave split (R7's verified mappings): W_N=4 -> 320 KB/tile LDS.
//  * manual A-frag double-buffer across kt (R7's failure was A-load chains
//    at VGPR=52; launch_bounds(512,2) + hand pipeline fixes it).
//  * lgkmcnt-ONLY barriers (asm "s_waitcnt lgkmcnt(0); s_barrier"): output
//    stores + child prefetch stay in flight across barriers (T4).
//  * nontemporal out-stores: don't evict L2-resident weight panels.
//  * R9's cross-tile reg prefetch (32 transient VGPRs), grid 512 persistent.
//
// MFMA conventions (verified R1..R9, absmax 0.03125):
//   A-frag: lane holds A[row = lane&15][k = 8*(lane>>4)+i], i=0..7
//   B-frag: lane holds B[k = 8*(lane>>4)+i][col = lane&15]
//   C/D  : lane holds C[row = 4*(lane>>4)+reg][col = lane&15]

typedef float f32x4 __attribute__((ext_vector_type(4)));
typedef short bf16x8 __attribute__((ext_vector_type(8)));
typedef unsigned int u32;
typedef u32 u32x4 __attribute__((ext_vector_type(4)));

#define BARRIER_LGKM() asm volatile("s_waitcnt lgkmcnt(0)\n\ts_barrier" ::: "memory")

__device__ __forceinline__ u32 pk2bf(float a, float b) {
    __hip_bfloat162 h2 = __float22bfloat162_rn(make_float2(a, b));
    u32 r;
    __builtin_memcpy(&r, &h2, 4);
    return r;
}

// Pack weights into per-lane MFMA A-fragment order; parent folded into W1.
// halfword[((kt*16 + nt)*64 + lane)*8 + i] = bf16(W'[nt*16 + (lane&15)][kt*32 + 8*(lane>>4) + i])
__global__ __launch_bounds__(256) void pack_w_kernel(
    const float* __restrict__ W1, const float* __restrict__ W2,
    const float* __restrict__ parent, unsigned short* __restrict__ wp)
{
    int t = blockIdx.x * 256 + threadIdx.x;   // 0..16383
    int sel = t >> 13;
    int tt = t & 8191;
    int lane = tt & 63;
    int nt = (tt >> 6) & 15;
    int kt = tt >> 10;
    int n = nt * 16 + (lane & 15);
    int k0 = kt * 32 + 8 * (lane >> 4);
    const float* W = sel ? W2 : W1;
    const float* src = W + n * 256 + k0;
    f32x4 a = *(const f32x4*)src;
    f32x4 b = *(const f32x4*)(src + 4);
    if (sel == 0) {                            // fold parent into W1
        a *= *(const f32x4*)(parent + k0);
        b *= *(const f32x4*)(parent + k0 + 4);
    }
    u32x4 d;
    d.x = pk2bf(a.x, a.y);
    d.y = pk2bf(a.z, a.w);
    d.z = pk2bf(b.x, b.y);
    d.w = pk2bf(b.z, b.w);
    *(u32x4*)(wp + (size_t)t * 8) = d;
}

__global__ __launch_bounds__(512, 2) void fused_mlp(
    const float* __restrict__ child,
    const float* __restrict__ b1, const float* __restrict__ b2,
    const unsigned short* __restrict__ w1p, const unsigned short* __restrict__ w2p,
    float* __restrict__ out, int n_rows)
{
    // frags: frag (mf, kt) at halfword (mf*8+kt)*512 + lane*8   (mf<4, kt<8)
    __shared__ __align__(16) unsigned short xf[16384];   // 32 KiB x-frags
    __shared__ __align__(16) unsigned short hf[16384];   // 32 KiB h-frags
    __shared__ __align__(16) float bias[512];            // [0..255]=b1, [256..511]=b2

    const int tid = threadIdx.x;
    const int lane = tid & 63;
    const int w = tid >> 6;        // wave 0..7
    const int m16 = lane & 15;
    const int g = lane >> 4;
    // stage role: rows [16*mfS,+16), k-half (w&1)*128
    const int mfS = w >> 1;
    const int khalf = (w & 1) * 128;
    // compute role: rows [mg*32,+32) (mf = 2mg+mfl), cols [ng*64,+64) (nt = ng*4+q)
    const int mg = w >> 2;         // 0..1
    const int ng = w & 3;          // 0..3

    if (tid < 256) bias[tid] = b1[tid];
    else           bias[tid] = b2[tid - 256];

    const int n_tiles = (n_rows + 63) >> 6;    // 3125 (200000 = 64*3125)

    // transient-held child rows for the NEXT tile (32 VGPRs)
    f32x4 c[8];
    auto load_rows = [&](int tile) {
        long row = (long)tile * 64 + mfS * 16 + m16;
        long lim = (long)n_rows - 1;
        if (row > lim) row = lim;              // safety clamp
        const float* cp = child + row * 256 + khalf + 8 * g;
        #pragma unroll
        for (int kt = 0; kt < 4; ++kt) {
            c[2 * kt]     = *(const f32x4*)(cp + kt * 32);
            c[2 * kt + 1] = *(const f32x4*)(cp + kt * 32 + 4);
        }
    };
    auto stage = [&]() {                       // cvt held regs -> x-frags
        #pragma unroll
        for (int kt = 0; kt < 4; ++kt) {
            u32x4 u;
            u.x = pk2bf(c[2 * kt].x, c[2 * kt].y);
            u.y = pk2bf(c[2 * kt].z, c[2 * kt].w);
            u.z = pk2bf(c[2 * kt + 1].x, c[2 * kt + 1].y);
            u.w = pk2bf(c[2 * kt + 1].z, c[2 * kt + 1].w);
            *(u32x4*)&xf[((mfS * 8 + (w & 1) * 4 + kt) * 64 + lane) * 8] = u;
        }
    };

    // prologue
    load_rows(blockIdx.x);
    stage();
    BARRIER_LGKM();                            // bias + xf(first) ready

    for (int tile = blockIdx.x; tile < n_tiles; tile += gridDim.x) {
        const int row0 = tile * 64;
        const int nxt = tile + gridDim.x;
        const bool have_nxt = nxt < n_tiles;   // block-uniform

        if (have_nxt) load_rows(nxt);          // vmem in flight across layer 1

        // ---- layer 1: A from L2 (manual double-buffer), B from xf ----
        f32x4 acc1[2][4];
        #pragma unroll
        for (int q = 0; q < 4; ++q) {
            f32x4 bv = *(const f32x4*)&bias[(ng * 4 + q) * 16 + 4 * g];
            acc1[0][q] = bv;
            acc1[1][q] = bv;
        }
        {
            bf16x8 a[2][4];
            #pragma unroll
            for (int q = 0; q < 4; ++q)
                a[0][q] = *(const bf16x8*)(w1p + (size_t)((0 * 16 + ng * 4 + q) * 64 + lane) * 8);
            #pragma unroll
            for (int kt = 0; kt < 8; ++kt) {
                if (kt < 7) {
                    #pragma unroll
                    for (int q = 0; q < 4; ++q)
                        a[(kt + 1) & 1][q] = *(const bf16x8*)(w1p + (size_t)(((kt + 1) * 16 + ng * 4 + q) * 64 + lane) * 8);
                }
                #pragma unroll
                for (int mfl = 0; mfl < 2; ++mfl) {
                    bf16x8 bfrag = *(const bf16x8*)&xf[(((mg * 2 + mfl) * 8 + kt) * 64 + lane) * 8];
                    acc1[mfl][0] = __builtin_amdgcn_mfma_f32_16x16x32_bf16(a[kt & 1][0], bfrag, acc1[mfl][0], 0, 0, 0);
                    acc1[mfl][1] = __builtin_amdgcn_mfma_f32_16x16x32_bf16(a[kt & 1][1], bfrag, acc1[mfl][1], 0, 0, 0);
                    acc1[mfl][2] = __builtin_amdgcn_mfma_f32_16x16x32_bf16(a[kt & 1][2], bfrag, acc1[mfl][2], 0, 0, 0);
                    acc1[mfl][3] = __builtin_amdgcn_mfma_f32_16x16x32_bf16(a[kt & 1][3], bfrag, acc1[mfl][3], 0, 0, 0);
                }
            }
        }

        // ---- relu + pack h -> h-frags ----
        // lane holds h[n = (ng*4+q)*16 + 4g + r][m = (mg*2+mfl)*16 + m16]
        // frag (mf, kt2 = ntg>>1), jj = ntg&1:
        //   lane' = 16*(2jj + (g>>1)) + m16, halfwords 4*(g&1) + r
        #pragma unroll
        for (int mfl = 0; mfl < 2; ++mfl) {
            #pragma unroll
            for (int q = 0; q < 4; ++q) {
                f32x4 v = acc1[mfl][q];
                v.x = fmaxf(v.x, 0.0f); v.y = fmaxf(v.y, 0.0f);
                v.z = fmaxf(v.z, 0.0f); v.w = fmaxf(v.w, 0.0f);
                const int ntg = ng * 4 + q;
                const int kt2 = ntg >> 1;
                const int jj = ntg & 1;
                u32* dst = (u32*)&hf[(((mg * 2 + mfl) * 8 + kt2) * 64 +
                                      16 * (2 * jj + (g >> 1)) + m16) * 8 + 4 * (g & 1)];
                dst[0] = pk2bf(v.x, v.y);
                dst[1] = pk2bf(v.z, v.w);
            }
        }
        BARRIER_LGKM();                        // BAR_A: hf visible; xf reads done

        // ---- stage next tile's x-frags (overwrite safe) ----
        if (have_nxt) stage();

        // ---- layer 2: A from L2 (double-buffer), B from hf ----
        f32x4 acc2[2][4];
        #pragma unroll
        for (int q = 0; q < 4; ++q) {
            f32x4 bv = *(const f32x4*)&bias[256 + (ng * 4 + q) * 16 + 4 * g];
            acc2[0][q] = bv;
            acc2[1][q] = bv;
        }
        {
            bf16x8 a[2][4];
            #pragma unroll
            for (int q = 0; q < 4; ++q)
                a[0][q] = *(const bf16x8*)(w2p + (size_t)((0 * 16 + ng * 4 + q) * 64 + lane) * 8);
            #pragma unroll
            for (int kt = 0; kt < 8; ++kt) {
                if (kt < 7) {
                    #pragma unroll
                    for (int q = 0; q < 4; ++q)
                        a[(kt + 1) & 1][q] = *(const bf16x8*)(w2p + (size_t)(((kt + 1) * 16 + ng * 4 + q) * 64 + lane) * 8);
                }
                #pragma unroll
                for (int mfl = 0; mfl < 2; ++mfl) {
                    bf16x8 hfrag = *(const bf16x8*)&hf[(((mg * 2 + mfl) * 8 + kt) * 64 + lane) * 8];
                    acc2[mfl][0] = __builtin_amdgcn_mfma_f32_16x16x32_bf16(a[kt & 1][0], hfrag, acc2[mfl][0], 0, 0, 0);
                    acc2[mfl][1] = __builtin_amdgcn_mfma_f32_16x16x32_bf16(a[kt & 1][1], hfrag, acc2[mfl][1], 0, 0, 0);
                    acc2[mfl][2] = __builtin_amdgcn_mfma_f32_16x16x32_bf16(a[kt & 1][2], hfrag, acc2[mfl][2], 0, 0, 0);
                    acc2[mfl][3] = __builtin_amdgcn_mfma_f32_16x16x32_bf16(a[kt & 1][3], hfrag, acc2[mfl][3], 0, 0, 0);
                }
            }
        }

        // ---- relu + nontemporal store ----
        // lane holds out[m = (mg*2+mfl)*16 + m16][n2 = (ng*4+q)*16 + 4g + r]
        #pragma unroll
        for (int mfl = 0; mfl < 2; ++mfl) {
            const int m = (mg * 2 + mfl) * 16 + m16;
            if (row0 + m < n_rows) {
                float* orow = out + (size_t)(row0 + m) * 256 + 4 * g;
                #pragma unroll
                for (int q = 0; q < 4; ++q) {
                    f32x4 v = acc2[mfl][q];
                    v.x = fmaxf(v.x, 0.0f); v.y = fmaxf(v.y, 0.0f);
                    v.z = fmaxf(v.z, 0.0f); v.w = fmaxf(v.w, 0.0f);
                    __builtin_nontemporal_store(v, (f32x4*)(orow + (ng * 4 + q) * 16));
                }
            }
        }
        BARRIER_LGKM();                        // BAR_B: xf(t+1) visible; hf reads done
    }
}

extern "C" void kernel_launch(void* const* d_in, const int* in_sizes, int n_in,
                              void* d_out, int out_size, void* d_ws, size_t ws_size,
                              hipStream_t stream) {
    const float* parent = (const float*)d_in[0];
    const float* child  = (const float*)d_in[1];
    const float* W1     = (const float*)d_in[2];
    const float* b1     = (const float*)d_in[3];
    const float* W2     = (const float*)d_in[4];
    const float* b2     = (const float*)d_in[5];
    float* out = (float*)d_out;

    unsigned short* wp = (unsigned short*)d_ws;   // [0..65535]=W1' frags, [65536..131071]=W2 frags
    const int n_rows = in_sizes[1] / 256;         // 200000

    pack_w_kernel<<<64, 256, 0, stream>>>(W1, W2, parent, wp);
    fused_mlp<<<512, 512, 0, stream>>>(child, b1, b2,
                                       wp, wp + 65536, out, n_rows);
}